// Round 5
// baseline (304.555 us; speedup 1.0000x reference)
//
#include <hip/hip_runtime.h>

#define NN   16
#define CC   3
#define FOUT 64
#define HH   256
#define WW   256
#define KK   3
#define HO   254
#define WO   254
#define PLANE  (HO * WO)            // 64516 (divisible by 4 -> chunks never cross planes)
#define NELEM  (NN * FOUT * PLANE)  // 66,064,384
#define NCHUNK (NELEM / 4)          // 16,516,096

typedef float f32x4_a16 __attribute__((ext_vector_type(4), aligned(16)));
typedef float f32x4_a8  __attribute__((ext_vector_type(4), aligned(8)));

// Flat-sweep conv: output is written in LINEAR address order machine-wide,
// exactly like the 6.4 TB/s fill kernel (16B-aligned dwordx4, full 64B lines,
// one contiguous ~8MB frontier). Inputs (4MB, channel 0 only) are L2-resident.
__global__ __launch_bounds__(256) void conv2dcq_kernel(
    const float* __restrict__ x,       // (N, C, H, W)
    const float* __restrict__ weight,  // (F, C, K, K)
    const float* __restrict__ bias,    // (F,)
    float* __restrict__ out)           // (N, F, HO, WO)
{
    // Weights (channel CC-1) + bias: [0..8]=w, [9]=bias, padded to 12 floats.
    __shared__ __align__(16) float w_lds[FOUT][12];
    const int tid = threadIdx.x;
    for (int idx = tid; idx < FOUT * 10; idx += 256) {
        const int f = idx / 10, k = idx - f * 10;
        w_lds[f][k] = (k < 9)
            ? weight[f * (CC * KK * KK) + (CC - 1) * (KK * KK) + k]
            : bias[f];
    }
    __syncthreads();

    const unsigned stride = gridDim.x * 256u;
    for (unsigned c = blockIdx.x * 256u + (unsigned)tid; c < NCHUNK; c += stride) {
        const unsigned e0    = c * 4u;             // flat element index (x16B aligned)
        const unsigned plane = e0 / PLANE;         // compiler magic-mul
        const unsigned rem   = e0 - plane * PLANE;
        const unsigned i0    = rem / WO;           // output row
        const unsigned j0    = rem - i0 * WO;      // output col: always EVEN, 0..252
        const unsigned n     = plane >> 6;
        const unsigned f     = plane & 63u;

        // Wave-uniform f except at (rare) plane-boundary waves -> LDS broadcast.
        const f32x4_a16 w0 = *(const f32x4_a16*)&w_lds[f][0];
        const f32x4_a16 w1 = *(const f32x4_a16*)&w_lds[f][4];
        const float2    wb = *(const float2*)   &w_lds[f][8];
        const float wv[9] = { w0.x, w0.y, w0.z, w0.w,
                              w1.x, w1.y, w1.z, w1.w, wb.x };
        const float bv = wb.y;

        const float* xp = x + (size_t)n * (CC * HH * WW) + (size_t)i0 * WW + j0;
        f32x4_a16 acc = { bv, bv, bv, bv };

        if (j0 != 252u) {
            // In-row chunk: cols j0..j0+3 from input cols j0..j0+5 (j0 even -> 8B aligned).
            #pragma unroll
            for (int r = 0; r < 3; ++r) {
                const f32x4_a8 a = *(const f32x4_a8*)(xp + r * WW);
                const float2   b = *(const float2*)  (xp + r * WW + 4);
                const float win[6] = { a.x, a.y, a.z, a.w, b.x, b.y };
                #pragma unroll
                for (int dc = 0; dc < 3; ++dc) {
                    const float wq = wv[r * 3 + dc];
                    acc.x = fmaf(wq, win[dc + 0], acc.x);
                    acc.y = fmaf(wq, win[dc + 1], acc.y);
                    acc.z = fmaf(wq, win[dc + 2], acc.z);
                    acc.w = fmaf(wq, win[dc + 3], acc.w);
                }
            }
        } else {
            // Row-crossing chunk (j0==252): elems 0,1 = (i0, cols 252,253);
            // elems 2,3 = (i0+1, cols 0,1). Both windows 16B-aligned.
            // i0 <= 252 here (rem%4==0 forbids i0==253 with j0==252) -> rows <= 255 in-bounds.
            #pragma unroll
            for (int r = 0; r < 3; ++r) {
                const f32x4_a16 u = *(const f32x4_a16*)(xp + r * WW);            // (i0+r,   252..255)
                const f32x4_a16 v = *(const f32x4_a16*)(xp + (r + 1) * WW - 252);// (i0+r+1, 0..3)
                const float uu[4] = { u.x, u.y, u.z, u.w };
                const float vv[4] = { v.x, v.y, v.z, v.w };
                #pragma unroll
                for (int dc = 0; dc < 3; ++dc) {
                    const float wq = wv[r * 3 + dc];
                    acc.x = fmaf(wq, uu[dc + 0], acc.x);
                    acc.y = fmaf(wq, uu[dc + 1], acc.y);
                    acc.z = fmaf(wq, vv[dc + 0], acc.z);
                    acc.w = fmaf(wq, vv[dc + 1], acc.w);
                }
            }
        }

        *(f32x4_a16*)(out + e0) = acc;   // 16B-aligned, linear machine-wide sweep
    }
}

extern "C" void kernel_launch(void* const* d_in, const int* in_sizes, int n_in,
                              void* d_out, int out_size, void* d_ws, size_t ws_size,
                              hipStream_t stream) {
    const float* x      = (const float*)d_in[0];
    const float* weight = (const float*)d_in[1];
    const float* bias   = (const float*)d_in[2];
    float* out          = (float*)d_out;

    // 2048 blocks (8/CU): each sweep frontier is ~8MB of contiguous output,
    // marching linearly through the buffer — the fill kernel's pattern.
    conv2dcq_kernel<<<2048, 256, 0, stream>>>(x, weight, bias, out);
}

// Round 6
// 280.637 us; speedup vs baseline: 1.0852x; 1.0852x over previous
//
#include <hip/hip_runtime.h>

#define NN   16
#define CC   3
#define FOUT 64
#define HH   256
#define WW   256
#define KK   3
#define HO   254
#define WO   254
#define PLANE (HO * WO)

typedef float f32x4    __attribute__((ext_vector_type(4), aligned(16)));
typedef float f32x4_a8 __attribute__((ext_vector_type(4), aligned(8)));

// Row-pair kernel: each wave owns output rows (i0, i0+1) of one image and
// loops over all 64 filters. Input rows i0..i0+3 live in registers (loaded
// ONCE — the fast-family property; in-loop loads were the R4/R5 regression).
// Per filter the wave writes 2032B contiguous (2 adjacent rows), double the
// burst length of the 1-row variant, and the tail case disappears
// (127 pairs per image exactly).
__global__ __launch_bounds__(256) void conv2dcq_kernel(
    const float* __restrict__ x,       // (N, C, H, W)
    const float* __restrict__ weight,  // (F, C, K, K)
    const float* __restrict__ bias,    // (F,)
    float* __restrict__ out)           // (N, F, HO, WO)
{
    __shared__ __align__(16) float w_lds[FOUT][12];   // [0..8]=w, [9]=bias

    const int tid = threadIdx.x;
    for (int idx = tid; idx < FOUT * 10; idx += 256) {
        const int f = idx / 10, k = idx - f * 10;
        w_lds[f][k] = (k < 9)
            ? weight[f * (CC * KK * KK) + (CC - 1) * (KK * KK) + k]
            : bias[f];
    }
    __syncthreads();

    const int lane = tid & 63;
    const int wave = tid >> 6;

    // 2032 wave-tasks (16 images * 127 row-pairs). Bijective XCD swizzle:
    // 2032 = 8 * 254.
    const int g   = (int)blockIdx.x * 4 + wave;
    const int swz = (g & 7) * 254 + (g >> 3);
    const unsigned n  = (unsigned)swz / 127u;
    const int      ip = swz - (int)n * 127;
    const int      i0 = 2 * ip;                 // even start row

    // Lane windows. Lane 63 reads A from col 252 and B from col 0: the even
    // row's stored lanes (acc[0,1] = cols 252,253) and the odd row's stored
    // lanes (acc[2,3] = cols 0,1) are computed by the same branch-free code.
    const int colA = (lane < 63) ? 4 * lane     : 252;
    const int colB = (lane < 63) ? 4 * lane + 4 : 0;

    const float* xp = x + (size_t)n * (CC * HH * WW) + (size_t)i0 * WW;
    f32x4 A[4], B[4];                           // input rows i0..i0+3
    #pragma unroll
    for (int r = 0; r < 4; ++r) {
        A[r] = *(const f32x4*)(xp + r * WW + colA);   // input rows are 1KB -> 16B aligned
        B[r] = *(const f32x4*)(xp + r * WW + colB);
    }

    // Window registers. Even output row i0 uses input rows 0..2, window
    // [A0 A1 A2 A3 B0 B1] (out cols 4l..4l+3). Odd row i0+1 uses rows 1..3,
    // window [A2 A3 B0 B1 B2 B3] (out cols 4l+2..4l+5).
    float winE[3][6], winO[3][6];
    #pragma unroll
    for (int r = 0; r < 3; ++r) {
        winE[r][0] = A[r][0]; winE[r][1] = A[r][1]; winE[r][2] = A[r][2];
        winE[r][3] = A[r][3]; winE[r][4] = B[r][0]; winE[r][5] = B[r][1];
        winO[r][0] = A[r+1][2]; winO[r][1] = A[r+1][3]; winO[r][2] = B[r+1][0];
        winO[r][3] = B[r+1][1]; winO[r][4] = B[r+1][2]; winO[r][5] = B[r+1][3];
    }

    float* op = out + (size_t)n * (FOUT * PLANE) + (size_t)i0 * WO;

    #pragma unroll 4
    for (int f = 0; f < FOUT; ++f) {
        const f32x4  w0 = *(const f32x4*)(&w_lds[f][0]);   // ds_read_b128
        const f32x4  w1 = *(const f32x4*)(&w_lds[f][4]);   // ds_read_b128
        const float2 wb = *(const float2*)(&w_lds[f][8]);  // w8, bias
        const float wv[9] = { w0.x, w0.y, w0.z, w0.w,
                              w1.x, w1.y, w1.z, w1.w, wb.x };
        const float bv = wb.y;

        float accE[4] = { bv, bv, bv, bv };
        float accO[4] = { bv, bv, bv, bv };
        #pragma unroll
        for (int dr = 0; dr < 3; ++dr)
            #pragma unroll
            for (int dc = 0; dc < 3; ++dc) {
                const float wq = wv[dr * 3 + dc];
                #pragma unroll
                for (int c = 0; c < 4; ++c) {
                    accE[c] = fmaf(wq, winE[dr][dc + c], accE[c]);
                    accO[c] = fmaf(wq, winO[dr][dc + c], accO[c]);
                }
            }

        // Even row base ≡ 0 (mod 16): store at col 4l. Odd row base ≡ 8:
        // store at col 4l+2 -> byte ≡ 0 (mod 16). All x4 stores aligned,
        // 2032B contiguous per wave per filter.
        if (lane < 63) {
            f32x4 ve; ve.x=accE[0]; ve.y=accE[1]; ve.z=accE[2]; ve.w=accE[3];
            f32x4 vo; vo.x=accO[0]; vo.y=accO[1]; vo.z=accO[2]; vo.w=accO[3];
            *(f32x4*)(op + colA)          = ve;
            *(f32x4*)(op + WO + colA + 2) = vo;
        } else {
            *(float2*)(op + 252) = make_float2(accE[0], accE[1]);  // cols 252,253
            *(float2*)(op + WO)  = make_float2(accO[2], accO[3]);  // cols 0,1
        }
        op += PLANE;
    }
}

extern "C" void kernel_launch(void* const* d_in, const int* in_sizes, int n_in,
                              void* d_out, int out_size, void* d_ws, size_t ws_size,
                              hipStream_t stream) {
    const float* x      = (const float*)d_in[0];
    const float* weight = (const float*)d_in[1];
    const float* bias   = (const float*)d_in[2];
    float* out          = (float*)d_out;

    const int total_waves = NN * (HO / 2);     // 2032 row-pair waves
    const int blocks = total_waves / 4;        // 508 blocks
    conv2dcq_kernel<<<blocks, 256, 0, stream>>>(x, weight, bias, out);
}